// Round 11
// baseline (214.854 us; speedup 1.0000x reference)
//
#include <hip/hip_runtime.h>

#define BB 8
#define NN 8192
#define SS 2048
#define CC 64
#define NS 32
#define COUT 67        // 3 xyz + 64 feature channels
#define QT 8           // queries per block (each wave scans 2)
#define SLOTS (QT*NS)  // 256 (query,sample) slots per block
#define SP 260         // padded c-major LDS stride (floats): 2-way banks, free
#define REP 2          // DIAGNOSTIC: repeat R9-best kernel to clear the ~88us
                       // top-5 cutoff and expose ITS counters (R7 profiled the
                       // older R5 layout). Idempotent -> absmax stays 0.

typedef float f32x4 __attribute__((ext_vector_type(4)));

// -------- Fused kernel: R9-best structure, REP=2 for counter visibility -----
__global__ __launch_bounds__(256, 6) void fused_rep2_diag(
    const float* __restrict__ xyz,      // (B, N, 3)
    const float* __restrict__ new_xyz,  // (B, S, 3)
    const float* __restrict__ feat,     // (B, N, C)
    float* __restrict__ out)            // (B, 67, S, NS)
{
#pragma clang fp contract(off)
    __shared__ float fh[16 * SP];        // 16.6 KB: 16 channels x 256 slots
    __shared__ float xt[3 * SP];         // 3.1 KB:  3 xyz planes x 256 slots
    __shared__ int idx_sh[SLOTS];        // 1 KB

    const int t   = threadIdx.x;
    const int w   = t >> 6;              // wave 0..3
    const int ln  = t & 63;
    const int bid = blockIdx.x;          // 0..2047, b-fastest (XCD-affine)
    const int b     = bid & 7;
    const int sTile = bid >> 3;          // 0..255
    const int s0 = sTile * QT;

    for (int rep = 0; rep < REP; ++rep) {
    // ================= Phase 1: ball-query scan (bit-exact) =================
    for (int qi = 0; qi < 2; ++qi) {
        const int q = (qi << 2) + w;
        const int s = s0 + q;
        const float R2 = 0.04f;          // strict '<' matches ref

        const float* ctr = new_xyz + ((size_t)b * SS + s) * 3;
        const float cx = ctr[0], cy = ctr[1], cz = ctr[2];
        const float* xb = xyz + (size_t)b * NN * 3;

        int* myidx = idx_sh + (q << 5);
        const unsigned long long lt = (1ull << ln) - 1ull;

        int total = 0;
        int firstIdx = -1;
        for (int j0 = 0; j0 < NN && total < NS; j0 += 256) {
            // 48B-aligned: (j0 + 4*ln)*12 bytes is a multiple of 48
            const float4* p4 = (const float4*)(xb + (size_t)(j0 + (ln << 2)) * 3);
            const float4 A  = p4[0];   // x0 y0 z0 x1
            const float4 Bv = p4[1];   // y1 z1 x2 y2
            const float4 Cv = p4[2];   // z2 x3 y3 z3
            float d2v[4];
            {
                const float dx = A.x - cx, dy = A.y - cy, dz = A.z - cz;
                float d2 = dx * dx; d2 = d2 + dy * dy; d2 = d2 + dz * dz;
                d2v[0] = d2;
            }
            {
                const float dx = A.w - cx, dy = Bv.x - cy, dz = Bv.y - cz;
                float d2 = dx * dx; d2 = d2 + dy * dy; d2 = d2 + dz * dz;
                d2v[1] = d2;
            }
            {
                const float dx = Bv.z - cx, dy = Bv.w - cy, dz = Cv.x - cz;
                float d2 = dx * dx; d2 = d2 + dy * dy; d2 = d2 + dz * dz;
                d2v[2] = d2;
            }
            {
                const float dx = Cv.y - cx, dy = Cv.z - cy, dz = Cv.w - cz;
                float d2 = dx * dx; d2 = d2 + dy * dy; d2 = d2 + dz * dz;
                d2v[3] = d2;
            }

            unsigned long long M[4];
#pragma unroll
            for (int u = 0; u < 4; ++u) M[u] = __ballot(d2v[u] < R2);

            if (firstIdx < 0) {
                int fmin = 0x7fffffff;
#pragma unroll
                for (int u = 0; u < 4; ++u)
                    if (M[u] != 0ull) {
                        const int j = j0 + (__builtin_ctzll(M[u]) << 2) + u;
                        fmin = (j < fmin) ? j : fmin;
                    }
                if (fmin != 0x7fffffff) firstIdx = fmin;
            }

            int below = 0;   // hits in earlier lanes (any u) -> smaller j
#pragma unroll
            for (int u = 0; u < 4; ++u) below += (int)__popcll(M[u] & lt);

            int own = 0;     // own hits with smaller u -> smaller j
#pragma unroll
            for (int u = 0; u < 4; ++u) {
                if (d2v[u] < R2) {
                    const int pos = total + below + own;
                    if (pos < NS) myidx[pos] = j0 + (ln << 2) + u;
                    ++own;
                }
            }
#pragma unroll
            for (int u = 0; u < 4; ++u) total += (int)__popcll(M[u]);
        }
        if (total < NS) {
            const int fill = (total > 0) ? firstIdx : 0;
            if (ln >= total && ln < NS) myidx[ln] = fill;
        }
    }
    __syncthreads();

    // ================= Phase 2: gather, quarter-channel staged ==============
    const int c4  = ln & 3;              // float4 index within 16-ch stage
    const int ms  = ln >> 2;             // 16 slots per wave-instr
    const float* fb = feat + (size_t)b * NN * CC;
    const size_t plane = (size_t)SS * NS;
    float* ob = out + ((size_t)b * COUT * SS + s0) * NS;

    // ---- xyz planes: one slot per thread, c-major xt[p][slot] ----
    {
        const int r = idx_sh[t];
        const int q = t >> 5;
        const float* ctr = new_xyz + ((size_t)b * SS + s0 + q) * 3;
        const float* p   = xyz + ((size_t)b * NN + r) * 3;
        xt[0 * SP + t] = p[0] - ctr[0];
        xt[1 * SP + t] = p[1] - ctr[1];
        xt[2 * SP + t] = p[2] - ctr[2];
    }

#pragma unroll
    for (int st = 0; st < 4; ++st) {
        if (st > 0) __syncthreads();     // prev write-out done reading fh

        // ---- stage st: channels 16st..16st+15 for all 256 slots ----
        float4 vv[4];
        int    mm[4];
#pragma unroll
        for (int i = 0; i < 4; ++i) {
            mm[i] = (w << 6) + (i << 4) + ms;
            vv[i] = *(const float4*)(fb + (size_t)idx_sh[mm[i]] * CC
                                     + (st << 4) + (c4 << 2));
        }
#pragma unroll
        for (int i = 0; i < 4; ++i) {
            fh[((c4 << 2) + 0) * SP + mm[i]] = vv[i].x;   // 2-way banks, free
            fh[((c4 << 2) + 1) * SP + mm[i]] = vv[i].y;
            fh[((c4 << 2) + 2) * SP + mm[i]] = vv[i].z;
            fh[((c4 << 2) + 3) * SP + mm[i]] = vv[i].w;
        }
        __syncthreads();

        // ---- write-out: one 1KB full-wave float4 store per plane ----
        if (st == 0) {
            for (int i = 0; i < 5; ++i) {
                const int tau = (i << 2) + w;
                if (tau < 19) {
                    const float* src = (tau < 3) ? (xt + tau * SP)
                                                 : (fh + (tau - 3) * SP);
                    const float4 v = *(const float4*)(src + (ln << 2));
                    *(float4*)(ob + (size_t)tau * plane + (ln << 2)) = v;
                }
            }
        } else {
#pragma unroll
            for (int i = 0; i < 4; ++i) {
                const int tau = (i << 2) + w;
                const float4 v = *(const float4*)(fh + tau * SP + (ln << 2));
                *(float4*)(ob + (size_t)(3 + (st << 4) + tau) * plane
                           + (ln << 2)) = v;
            }
        }
    }
    __syncthreads();   // rep boundary (defensive; ordering traced safe)
    }  // rep
}

extern "C" void kernel_launch(void* const* d_in, const int* in_sizes, int n_in,
                              void* d_out, int out_size, void* d_ws, size_t ws_size,
                              hipStream_t stream) {
    const float* xyz     = (const float*)d_in[0];
    const float* new_xyz = (const float*)d_in[1];
    const float* feat    = (const float*)d_in[2];
    float* out = (float*)d_out;
    (void)d_ws; (void)ws_size;   // idx lives in LDS

    fused_rep2_diag<<<dim3((BB * SS) / QT), dim3(256), 0, stream>>>(xyz, new_xyz, feat, out);
}

// Round 13
// 176.984 us; speedup vs baseline: 1.2140x; 1.2140x over previous
//
#include <hip/hip_runtime.h>

#define BB 8
#define NN 8192
#define SS 2048
#define CC 64
#define NS 32
#define COUT 67        // 3 xyz + 64 feature channels
#define QT 8           // queries per block (each wave scans 2)
#define SLOTS (QT*NS)  // 256 (query,sample) slots per block
#define SP 260         // padded c-major LDS stride (floats): 2-way banks, free

// ---------------- Fused kernel: scan + gather, full-residency ---------------
// R11 REP=2 diag on this structure: FETCH ~9.5 MB/rep, WRITE ~141 MB/rep --
// traffic is CLEAN (compulsory only); but Occupancy 42% (2048 blocks, 6/CU
// resident -> 1.33 rounds = idle tail) and eff BW 3.2 TB/s. This version:
// 8-channel stages -> 12.5 KB LDS, launch_bounds(256,8) -> 8 blocks/CU =
// ALL 2048 blocks co-resident (one round, no tail). Next-stage loads issue
// into registers before write-out (T14): L2 latency hides under stores.
// (R12 bench attempt died to container-acquisition failure; resubmitted
// verbatim after a hang-safety audit: all loops bounded, barriers uniform.)
__global__ __launch_bounds__(256, 8) void fused_kernel(
    const float* __restrict__ xyz,      // (B, N, 3)
    const float* __restrict__ new_xyz,  // (B, S, 3)
    const float* __restrict__ feat,     // (B, N, C)
    float* __restrict__ out)            // (B, 67, S, NS)
{
#pragma clang fp contract(off)
    __shared__ float fh[8 * SP];         // 8.3 KB: 8 channels x 256 slots
    __shared__ float xt[3 * SP];         // 3.1 KB: 3 xyz planes x 256 slots
    __shared__ int idx_sh[SLOTS];        // 1 KB          (total 12.5 KB)

    const int t   = threadIdx.x;
    const int w   = t >> 6;              // wave 0..3
    const int ln  = t & 63;
    const int bid = blockIdx.x;          // 0..2047, b-fastest (XCD-affine)
    const int b     = bid & 7;
    const int sTile = bid >> 3;          // 0..255
    const int s0 = sTile * QT;

    // ================= Phase 1: ball-query scan (bit-exact) =================
    // Wave w scans queries q = w and q = w+4 with the verified loop.
    for (int qi = 0; qi < 2; ++qi) {
        const int q = (qi << 2) + w;
        const int s = s0 + q;
        const float R2 = 0.04f;          // strict '<' matches ref

        const float* ctr = new_xyz + ((size_t)b * SS + s) * 3;
        const float cx = ctr[0], cy = ctr[1], cz = ctr[2];
        const float* xb = xyz + (size_t)b * NN * 3;

        int* myidx = idx_sh + (q << 5);
        const unsigned long long lt = (1ull << ln) - 1ull;

        int total = 0;
        int firstIdx = -1;
        for (int j0 = 0; j0 < NN && total < NS; j0 += 256) {
            // 48B-aligned: (j0 + 4*ln)*12 bytes is a multiple of 48
            const float4* p4 = (const float4*)(xb + (size_t)(j0 + (ln << 2)) * 3);
            const float4 A  = p4[0];   // x0 y0 z0 x1
            const float4 Bv = p4[1];   // y1 z1 x2 y2
            const float4 Cv = p4[2];   // z2 x3 y3 z3
            float d2v[4];
            {
                const float dx = A.x - cx, dy = A.y - cy, dz = A.z - cz;
                float d2 = dx * dx; d2 = d2 + dy * dy; d2 = d2 + dz * dz;
                d2v[0] = d2;
            }
            {
                const float dx = A.w - cx, dy = Bv.x - cy, dz = Bv.y - cz;
                float d2 = dx * dx; d2 = d2 + dy * dy; d2 = d2 + dz * dz;
                d2v[1] = d2;
            }
            {
                const float dx = Bv.z - cx, dy = Bv.w - cy, dz = Cv.x - cz;
                float d2 = dx * dx; d2 = d2 + dy * dy; d2 = d2 + dz * dz;
                d2v[2] = d2;
            }
            {
                const float dx = Cv.y - cx, dy = Cv.z - cy, dz = Cv.w - cz;
                float d2 = dx * dx; d2 = d2 + dy * dy; d2 = d2 + dz * dz;
                d2v[3] = d2;
            }

            unsigned long long M[4];
#pragma unroll
            for (int u = 0; u < 4; ++u) M[u] = __ballot(d2v[u] < R2);

            if (firstIdx < 0) {
                int fmin = 0x7fffffff;
#pragma unroll
                for (int u = 0; u < 4; ++u)
                    if (M[u] != 0ull) {
                        const int j = j0 + (__builtin_ctzll(M[u]) << 2) + u;
                        fmin = (j < fmin) ? j : fmin;
                    }
                if (fmin != 0x7fffffff) firstIdx = fmin;
            }

            int below = 0;   // hits in earlier lanes (any u) -> smaller j
#pragma unroll
            for (int u = 0; u < 4; ++u) below += (int)__popcll(M[u] & lt);

            int own = 0;     // own hits with smaller u -> smaller j
#pragma unroll
            for (int u = 0; u < 4; ++u) {
                if (d2v[u] < R2) {
                    const int pos = total + below + own;
                    if (pos < NS) myidx[pos] = j0 + (ln << 2) + u;
                    ++own;
                }
            }
#pragma unroll
            for (int u = 0; u < 4; ++u) total += (int)__popcll(M[u]);
        }
        if (total < NS) {
            const int fill = (total > 0) ? firstIdx : 0;
            if (ln >= total && ln < NS) myidx[ln] = fill;
        }
    }
    __syncthreads();

    // ================= Phase 2: gather, 8-channel staged, pipelined =========
    const int c2 = ln & 1;               // which float4 in the 8-ch segment
    const int ms = ln >> 1;              // 32 slots per wave-instr
    const float* fb = feat + (size_t)b * NN * CC;
    const size_t plane = (size_t)SS * NS;
    float* ob = out + ((size_t)b * COUT * SS + s0) * NS;

    // ---- xyz planes: one slot per thread, c-major xt[p][slot] ----
    {
        const int r = idx_sh[t];
        const int q = t >> 5;
        const float* ctr = new_xyz + ((size_t)b * SS + s0 + q) * 3;
        const float* p   = xyz + ((size_t)b * NN + r) * 3;
        xt[0 * SP + t] = p[0] - ctr[0];
        xt[1 * SP + t] = p[1] - ctr[1];
        xt[2 * SP + t] = p[2] - ctr[2];
    }

    // row base pointers (idx read once; reused by all 8 stages)
    const int m0 = (w << 6) + ms;        // slot for i=0
    const int m1 = m0 + 32;              // slot for i=1
    const float* rp0 = fb + (size_t)idx_sh[m0] * CC + (c2 << 2);
    const float* rp1 = fb + (size_t)idx_sh[m1] * CC + (c2 << 2);

    // prologue: stage-0 loads in flight
    float4 v0 = *(const float4*)(rp0);
    float4 v1 = *(const float4*)(rp1);

#pragma unroll
    for (int st = 0; st < 8; ++st) {
        // ---- LDS write from regs (banks: 16*c2 + 4j + ms%32 -> 2-way, free)
        fh[((c2 << 2) + 0) * SP + m0] = v0.x;
        fh[((c2 << 2) + 1) * SP + m0] = v0.y;
        fh[((c2 << 2) + 2) * SP + m0] = v0.z;
        fh[((c2 << 2) + 3) * SP + m0] = v0.w;
        fh[((c2 << 2) + 0) * SP + m1] = v1.x;
        fh[((c2 << 2) + 1) * SP + m1] = v1.y;
        fh[((c2 << 2) + 2) * SP + m1] = v1.z;
        fh[((c2 << 2) + 3) * SP + m1] = v1.w;

        // ---- prefetch next stage into regs (hides L2 under write-out) ----
        if (st < 7) {
            v0 = *(const float4*)(rp0 + ((st + 1) << 3));
            v1 = *(const float4*)(rp1 + ((st + 1) << 3));
        }
        __syncthreads();                 // fh (and xt at st=0) ready

        // ---- write-out: one 1KB full-wave float4 store per plane ----
        if (st == 0) {
            // planes 0..10: 3 xyz + ch 0..7
            for (int i = 0; i < 3; ++i) {
                const int tau = (i << 2) + w;
                if (tau < 11) {
                    const float* src = (tau < 3) ? (xt + tau * SP)
                                                 : (fh + (tau - 3) * SP);
                    const float4 v = *(const float4*)(src + (ln << 2));
                    *(float4*)(ob + (size_t)tau * plane + (ln << 2)) = v;
                }
            }
        } else {
#pragma unroll
            for (int i = 0; i < 2; ++i) {
                const int pl = (i << 2) + w;   // 0..7
                const float4 v = *(const float4*)(fh + pl * SP + (ln << 2));
                *(float4*)(ob + (size_t)(3 + (st << 3) + pl) * plane
                           + (ln << 2)) = v;
            }
        }
        if (st < 7) __syncthreads();     // fh free before next stage's write
    }
}

extern "C" void kernel_launch(void* const* d_in, const int* in_sizes, int n_in,
                              void* d_out, int out_size, void* d_ws, size_t ws_size,
                              hipStream_t stream) {
    const float* xyz     = (const float*)d_in[0];
    const float* new_xyz = (const float*)d_in[1];
    const float* feat    = (const float*)d_in[2];
    float* out = (float*)d_out;
    (void)d_ws; (void)ws_size;   // idx lives in LDS

    fused_kernel<<<dim3((BB * SS) / QT), dim3(256), 0, stream>>>(xyz, new_xyz, feat, out);
}

// Round 14
// 176.245 us; speedup vs baseline: 1.2191x; 1.0042x over previous
//
#include <hip/hip_runtime.h>

#define BB 8
#define NN 8192
#define SS 2048
#define CC 64
#define NS 32
#define COUT 67        // 3 xyz + 64 feature channels
#define QT 8           // queries per block: 2 subtiles of 4
#define SPA 132        // padded LDS stride (128 slots + 4): 2-way banks, free

// ---------------- Fused kernel: scan/gather phase-overlapped ----------------
// R11 diag: traffic compulsory (9.5 MB fetch / 141 MB write per rep).
// R13: full residency null -> not occupancy-bound. Remaining serial waste:
// (a) scan prefix (~12-15us VALU, store path idle), (b) per-stage
// vmcnt(0)-at-barrier store drains (VALU idle). Fix: 2 subtiles of 4
// queries; subtile B's scan chunks interleave into subtile A's gather
// stages (between load issue and barrier), filling both stalls. Scan chunk
// body is byte-identical to the verified loop -> absmax 0 preserved.
__global__ __launch_bounds__(256, 6) void fused_kernel(
    const float* __restrict__ xyz,      // (B, N, 3)
    const float* __restrict__ new_xyz,  // (B, S, 3)
    const float* __restrict__ feat,     // (B, N, C)
    float* __restrict__ out)            // (B, 67, S, NS)
{
#pragma clang fp contract(off)
    __shared__ float fh[16 * SPA];       // 8.25 KB: 16 channels x 128 slots
    __shared__ float xt[3 * SPA];        // 1.5 KB:  3 xyz planes x 128 slots
    __shared__ int idx_sh[256];          // 1 KB: [0..127]=A, [128..255]=B

    const int t   = threadIdx.x;
    const int w   = t >> 6;              // wave 0..3
    const int ln  = t & 63;
    const int bid = blockIdx.x;          // 0..2047, b-fastest (XCD-affine)
    const int b     = bid & 7;
    const int sTile = bid >> 3;          // 0..255
    const int s0 = sTile * QT;

    const float R2 = 0.04f;              // strict '<' matches ref
    const float* xb = xyz + (size_t)b * NN * 3;
    const unsigned long long lt = (1ull << ln) - 1ull;

    // Incremental scanner: processes up to maxc 256-pt chunks; state in
    // (j0r, total, firstIdx). Chunk body bit-identical to verified scan.
    auto scan_chunks = [&](float cx, float cy, float cz, int* myidx,
                           int& j0r, int& total, int& firstIdx, int maxc) {
        for (int c = 0; c < maxc && j0r < NN && total < NS; ++c) {
            const int j0 = j0r;
            // 48B-aligned: (j0 + 4*ln)*12 bytes is a multiple of 48
            const float4* p4 = (const float4*)(xb + (size_t)(j0 + (ln << 2)) * 3);
            const float4 A  = p4[0];   // x0 y0 z0 x1
            const float4 Bv = p4[1];   // y1 z1 x2 y2
            const float4 Cv = p4[2];   // z2 x3 y3 z3
            float d2v[4];
            { const float dx = A.x - cx, dy = A.y - cy, dz = A.z - cz;
              float d2 = dx * dx; d2 = d2 + dy * dy; d2 = d2 + dz * dz; d2v[0] = d2; }
            { const float dx = A.w - cx, dy = Bv.x - cy, dz = Bv.y - cz;
              float d2 = dx * dx; d2 = d2 + dy * dy; d2 = d2 + dz * dz; d2v[1] = d2; }
            { const float dx = Bv.z - cx, dy = Bv.w - cy, dz = Cv.x - cz;
              float d2 = dx * dx; d2 = d2 + dy * dy; d2 = d2 + dz * dz; d2v[2] = d2; }
            { const float dx = Cv.y - cx, dy = Cv.z - cy, dz = Cv.w - cz;
              float d2 = dx * dx; d2 = d2 + dy * dy; d2 = d2 + dz * dz; d2v[3] = d2; }

            unsigned long long M[4];
#pragma unroll
            for (int u = 0; u < 4; ++u) M[u] = __ballot(d2v[u] < R2);

            if (firstIdx < 0) {
                int fmin = 0x7fffffff;
#pragma unroll
                for (int u = 0; u < 4; ++u)
                    if (M[u] != 0ull) {
                        const int j = j0 + (__builtin_ctzll(M[u]) << 2) + u;
                        fmin = (j < fmin) ? j : fmin;
                    }
                if (fmin != 0x7fffffff) firstIdx = fmin;
            }

            int below = 0;   // hits in earlier lanes (any u) -> smaller j
#pragma unroll
            for (int u = 0; u < 4; ++u) below += (int)__popcll(M[u] & lt);

            int own = 0;     // own hits with smaller u -> smaller j
#pragma unroll
            for (int u = 0; u < 4; ++u) {
                if (d2v[u] < R2) {
                    const int pos = total + below + own;
                    if (pos < NS) myidx[pos] = j0 + (ln << 2) + u;
                    ++own;
                }
            }
#pragma unroll
            for (int u = 0; u < 4; ++u) total += (int)__popcll(M[u]);
            j0r += 256;
        }
    };

    // ================= Phase 1: scan subtile A (q = w), full ================
    {
        const float* ctrA = new_xyz + ((size_t)b * SS + s0 + w) * 3;
        int jA = 0, totA = 0, fA = -1;
        scan_chunks(ctrA[0], ctrA[1], ctrA[2], idx_sh + (w << 5),
                    jA, totA, fA, 32);
        if (totA < NS) {
            const int fill = (totA > 0) ? fA : 0;
            if (ln >= totA && ln < NS) idx_sh[(w << 5) + ln] = fill;
        }
    }
    __syncthreads();                     // idx_sh[0..127] ready

    // B-scan state (q = 4+w), advanced incrementally under gather-A
    const float* ctrB = new_xyz + ((size_t)b * SS + s0 + 4 + w) * 3;
    const float cbx = ctrB[0], cby = ctrB[1], cbz = ctrB[2];
    int jB = 0, totB = 0, fB = -1;
    int* myidxB = idx_sh + 128 + (w << 5);

    // ---- xt for A: threads 0..127, c-major xt[p][slot] ----
    if (t < 128) {
        const int r = idx_sh[t];
        const int q = t >> 5;
        const float* ctr = new_xyz + ((size_t)b * SS + s0 + q) * 3;
        const float* p   = xb + (size_t)r * 3;
        xt[0 * SPA + t] = p[0] - ctr[0];
        xt[1 * SPA + t] = p[1] - ctr[1];
        xt[2 * SPA + t] = p[2] - ctr[2];
    }

    const float* fb = feat + (size_t)b * NN * CC;
    const size_t plane = (size_t)SS * NS;
    float* ob = out + ((size_t)b * COUT * SS + s0) * NS;

    const int m  = t >> 1;               // slot 0..127 (two threads per slot)
    const int fq = t & 1;                // which 8-ch half of the 16-ch stage
    const int cb = fq << 3;              // LDS channel base 0/8
    const float* frowA = fb + (size_t)idx_sh[m] * CC + (fq << 3);

    // stores for one 16-ch stage; soff = 0 (A) or 128 (B)
    auto store_stage = [&](int st, int soff) {
        const int ofs = (ln & 31) << 2;  // 4 slots per lane, 512B runs
        if (st == 0) {
            // 19 planes: 3 xyz + ch 0..15; dual-plane wave tasks
            for (int i = 0; i < 3; ++i) {
                const int tt = (i << 2) + w;
                if (tt < 10) {
                    const int p = (tt << 1) + (ln >> 5);
                    if (p < 19) {
                        const float* src = (p < 3) ? (xt + p * SPA)
                                                   : (fh + (p - 3) * SPA);
                        const float4 v = *(const float4*)(src + ofs);
                        *(float4*)(ob + (size_t)p * plane + soff + ofs) = v;
                    }
                }
            }
        } else {
            // 16 planes: 3+16st .. 3+16st+15
            for (int i = 0; i < 2; ++i) {
                const int tt = (i << 2) + w;
                const int j  = (tt << 1) + (ln >> 5);     // 0..15
                const float4 v = *(const float4*)(fh + j * SPA + ofs);
                *(float4*)(ob + (size_t)(3 + (st << 4) + j) * plane
                           + soff + ofs) = v;
            }
        }
    };

    // ============ Phase 2a: gather A, B-scan interleaved ====================
#pragma unroll
    for (int st = 0; st < 4; ++st) {
        // issue this stage's loads first ...
        const float4 v0 = *(const float4*)(frowA + (st << 4));
        const float4 v1 = *(const float4*)(frowA + (st << 4) + 4);
        // ... then fill the latency + store-drain window with B's scan
        scan_chunks(cbx, cby, cbz, myidxB, jB, totB, fB, 4);
        __syncthreads();                 // prior stores' LDS reads done
        fh[(cb + 0) * SPA + m] = v0.x;   // 2 lanes/bank: free
        fh[(cb + 1) * SPA + m] = v0.y;
        fh[(cb + 2) * SPA + m] = v0.z;
        fh[(cb + 3) * SPA + m] = v0.w;
        fh[(cb + 4) * SPA + m] = v1.x;
        fh[(cb + 5) * SPA + m] = v1.y;
        fh[(cb + 6) * SPA + m] = v1.z;
        fh[(cb + 7) * SPA + m] = v1.w;
        __syncthreads();                 // fh (and xt at st=0) ready
        store_stage(st, 0);
    }

    // ============ Phase 2b: drain B scan, then gather B =====================
    scan_chunks(cbx, cby, cbz, myidxB, jB, totB, fB, 32);
    if (totB < NS) {
        const int fill = (totB > 0) ? fB : 0;
        if (ln >= totB && ln < NS) myidxB[ln] = fill;
    }
    __syncthreads();                     // idx_sh[128..] visible; A stores done

    if (t < 128) {                       // xt for B
        const int r = idx_sh[128 + t];
        const int q = 4 + (t >> 5);
        const float* ctr = new_xyz + ((size_t)b * SS + s0 + q) * 3;
        const float* p   = xb + (size_t)r * 3;
        xt[0 * SPA + t] = p[0] - ctr[0];
        xt[1 * SPA + t] = p[1] - ctr[1];
        xt[2 * SPA + t] = p[2] - ctr[2];
    }
    const float* frowB = fb + (size_t)idx_sh[128 + m] * CC + (fq << 3);

#pragma unroll
    for (int st = 0; st < 4; ++st) {
        const float4 v0 = *(const float4*)(frowB + (st << 4));
        const float4 v1 = *(const float4*)(frowB + (st << 4) + 4);
        __syncthreads();                 // prior stores' LDS reads done
        fh[(cb + 0) * SPA + m] = v0.x;
        fh[(cb + 1) * SPA + m] = v0.y;
        fh[(cb + 2) * SPA + m] = v0.z;
        fh[(cb + 3) * SPA + m] = v0.w;
        fh[(cb + 4) * SPA + m] = v1.x;
        fh[(cb + 5) * SPA + m] = v1.y;
        fh[(cb + 6) * SPA + m] = v1.z;
        fh[(cb + 7) * SPA + m] = v1.w;
        __syncthreads();                 // fh (and xt at st=0) ready
        store_stage(st, 128);
    }
}

extern "C" void kernel_launch(void* const* d_in, const int* in_sizes, int n_in,
                              void* d_out, int out_size, void* d_ws, size_t ws_size,
                              hipStream_t stream) {
    const float* xyz     = (const float*)d_in[0];
    const float* new_xyz = (const float*)d_in[1];
    const float* feat    = (const float*)d_in[2];
    float* out = (float*)d_out;
    (void)d_ws; (void)ws_size;   // idx lives in LDS

    fused_kernel<<<dim3((BB * SS) / QT), dim3(256), 0, stream>>>(xyz, new_xyz, feat, out);
}